// Round 15
// baseline (1536.402 us; speedup 1.0000x reference)
//
#include <hip/hip_runtime.h>

#define HW 16384   // 128*128
#define RSB 130    // padded row stride (pixels)
#define REP 10     // diagnostic amplification factor (idempotent kernels)

typedef short short8 __attribute__((ext_vector_type(8)));
typedef float f32x4 __attribute__((ext_vector_type(4)));
typedef unsigned short ushort8v __attribute__((ext_vector_type(8)));

__device__ __forceinline__ float b2f(unsigned short u) {
    return __uint_as_float(((unsigned)u) << 16);
}
__device__ __forceinline__ unsigned short f2b(float f) {
    unsigned u = __float_as_uint(f);
    return (unsigned short)((u + 0x7fffu + ((u >> 16) & 1u)) >> 16);
}

// ---------------------------------------------------------------------------
// One-shot prep: weight B-fragments + NHWC pack + border zeroing.  (r12)
// ---------------------------------------------------------------------------
__global__ __launch_bounds__(256) void prep_all(
    const float* __restrict__ X1, const float* __restrict__ X2,
    const float* __restrict__ w_bot,
    const float* __restrict__ wo0, const float* __restrict__ wo1,
    const float* __restrict__ wo2, const float* __restrict__ wo3,
    const float* __restrict__ wd0, const float* __restrict__ wd1,
    const float* __restrict__ wd2, const float* __restrict__ wd3,
    unsigned short* __restrict__ wBbot, unsigned short* __restrict__ wBoff,
    unsigned short* __restrict__ wdB,  unsigned short* __restrict__ in_nhwc,
    unsigned short* __restrict__ featA, unsigned short* __restrict__ featB,
    int rep) {
    const int N0 = 165888, N1 = N0 + 331776, N2 = N1 + 110592,
              N3 = N2 + 393216, N4 = N3 + 24768;
    for (int rr = 0; rr < rep; ++rr) {
        asm volatile("" ::: "memory");
        for (int idx = blockIdx.x * 256 + threadIdx.x; idx < N4; idx += 131072) {
            if (idx < N0) {
                int i = idx;
                int v = i & 7, lane = (i >> 3) & 63, t = i >> 9;
                int kc = t % 6; t /= 6;
                int tap = t % 9, nt = t / 9;
                int oc = nt * 16 + (lane & 15), cin = kc * 32 + (lane >> 4) * 8 + v;
                wBbot[i] = f2b(oc < 96 ? w_bot[(oc * 192 + cin) * 9 + tap] : 0.f);
            } else if (idx < N1) {
                int j = idx - N0;
                int l = j / 82944, i = j - l * 82944;
                const float* w = l == 0 ? wo0 : l == 1 ? wo1 : l == 2 ? wo2 : wo3;
                int v = i & 7, lane = (i >> 3) & 63, t = i >> 9;
                int kc = t % 3; t /= 3;
                int tap = t % 9, nt = t / 9;
                int oc = nt * 16 + (lane & 15), cin = kc * 32 + (lane >> 4) * 8 + v;
                wBoff[j] = f2b(oc < 81 ? w[(oc * 96 + cin) * 9 + tap] : 0.f);
            } else if (idx < N2) {
                int j = idx - N1;
                int l = j / 27648, i = j - l * 27648;
                const float* w = l == 0 ? wd0 : l == 1 ? wd1 : l == 2 ? wd2 : wd3;
                int v = i & 7, lane = (i >> 3) & 63, t = i >> 9;
                int nt = t & 1; t >>= 1;
                int tap = t % 9, g = t / 9;
                int oc = nt * 16 + (lane & 15), c = (lane >> 4) * 8 + v;
                wdB[j] = f2b(w[((g * 32 + oc) * 32 + c) * 9 + tap]);
            } else if (idx < N3) {
                int j = idx - N2;
                int cb = j >> 14, p = j & (HW - 1);
                int ch = cb * 8;
                int y = p >> 7, x = p & 127;
                ushort8v o;
#pragma unroll
                for (int q = 0; q < 8; ++q) {
                    int c = ch + q;
                    float v = (c < 96) ? X1[c * HW + p] : X2[(c - 96) * HW + p];
                    o[q] = f2b(v);
                }
                *(ushort8v*)(in_nhwc + (size_t)((y + 1) * RSB + (x + 1)) * 192 + ch) = o;
            } else {
                int j = idx - N3;
                int bp = j / 48, c8 = j - bp * 48;
                int y, x;
                if (bp < 130)      { y = 0;   x = bp; }
                else if (bp < 260) { y = 129; x = bp - 130; }
                else { int t2 = bp - 260; y = 1 + (t2 >> 1); x = (t2 & 1) ? 129 : 0; }
                size_t pix = (size_t)y * RSB + x;
                ushort8v z = {0, 0, 0, 0, 0, 0, 0, 0};
                if (c8 < 24)      *(ushort8v*)(in_nhwc + pix * 192 + c8 * 8) = z;
                else if (c8 < 36) *(ushort8v*)(featA + pix * 96 + (c8 - 24) * 8) = z;
                else              *(ushort8v*)(featB + pix * 96 + (c8 - 36) * 8) = z;
            }
        }
    }
}

// ---------------------------------------------------------------------------
// Bottom conv (192 -> 96), r12 structure: 32 px/block, 4 waves.
// ---------------------------------------------------------------------------
__global__ __launch_bounds__(256) void conv_bot(const unsigned short* __restrict__ in,
                                                const unsigned short* __restrict__ wB,
                                                unsigned short* __restrict__ outb,
                                                int rep) {
    const int tid = threadIdx.x;
    const int lane = tid & 63;
    const int wid = tid >> 6;
    const int msub = wid & 1, nh = wid >> 1;
    const int pbase = blockIdx.x * 32 + msub * 16;
    const int p = pbase + (lane & 15);
    const int y = p >> 7, x = p & 127;
    const int klane = lane >> 4;
    const unsigned short* arow = in + (size_t)((y + 1) * RSB + (x + 1)) * 192 + klane * 8;
    const unsigned short* wb = wB + (size_t)(nh * 3) * 9 * 6 * 512 + lane * 8;
    const int col = lane & 15;

    for (int rr = 0; rr < rep; ++rr) {
        asm volatile("" ::: "memory");
        f32x4 a0 = {0.f, 0.f, 0.f, 0.f};
        f32x4 a1 = {0.f, 0.f, 0.f, 0.f};
        f32x4 a2 = {0.f, 0.f, 0.f, 0.f};
#pragma unroll
        for (int tap = 0; tap < 9; ++tap) {
            const unsigned short* at = arow + ((tap / 3 - 1) * RSB + (tap % 3 - 1)) * 192;
#pragma unroll
            for (int kc = 0; kc < 6; ++kc) {
                short8 a  = *(const short8*)(at + kc * 32);
                short8 b0 = *(const short8*)(wb + ((0 * 9 + tap) * 6 + kc) * 512);
                short8 b1 = *(const short8*)(wb + ((1 * 9 + tap) * 6 + kc) * 512);
                short8 b2 = *(const short8*)(wb + ((2 * 9 + tap) * 6 + kc) * 512);
                a0 = __builtin_amdgcn_mfma_f32_16x16x32_bf16(a, b0, a0, 0, 0, 0);
                a1 = __builtin_amdgcn_mfma_f32_16x16x32_bf16(a, b1, a1, 0, 0, 0);
                a2 = __builtin_amdgcn_mfma_f32_16x16x32_bf16(a, b2, a2, 0, 0, 0);
            }
        }
#pragma unroll
        for (int r = 0; r < 4; ++r) {
            int pr = pbase + klane * 4 + r;
            int yy = pr >> 7, xx = pr & 127;
            size_t base = (size_t)((yy + 1) * RSB + (xx + 1)) * 96;
            outb[base + (nh * 3 + 0) * 16 + col] = f2b(a0[r]);
            outb[base + (nh * 3 + 1) * 16 + col] = f2b(a1[r]);
            outb[base + (nh * 3 + 2) * 16 + col] = f2b(a2[r]);
        }
    }
}

// ---------------------------------------------------------------------------
// FUSED offset-conv + DCN layer, r12 structure: 32 px/block, 4 waves,
// 2 blocks/CU, zero-border clamp addressing, pipelined gathers.
// ---------------------------------------------------------------------------
__global__ __launch_bounds__(256) void offdcn_kernel(
    const unsigned short* __restrict__ feat,
    const unsigned short* __restrict__ wBoff,
    const unsigned short* __restrict__ wdB,
    const float* __restrict__ b_d,
    void* __restrict__ outp, int last, int rep) {
    __shared__ float s_off[32][97];

    const int tid = threadIdx.x;
    const int lane = tid & 63;
    const int w = tid >> 6;
    const int col = lane & 15, klane = lane >> 4;
    const int pb = ((blockIdx.x & 7) << 6) + (blockIdx.x >> 3);
    const int P0 = pb * 32;

    for (int rr = 0; rr < rep; ++rr) {
        asm volatile("" ::: "memory");
        // ---------------- phase A: offset conv ----------------
        {
            const int pf = w >> 1, nh = w & 1;
            const int p = P0 + pf * 16 + col;
            const int y = p >> 7, x = p & 127;
            const unsigned short* arow = feat + (size_t)((y + 1) * RSB + (x + 1)) * 96 + klane * 8;
            const unsigned short* wb = wBoff + (size_t)(nh * 3) * 9 * 3 * 512 + lane * 8;

            f32x4 a0 = {0.f, 0.f, 0.f, 0.f};
            f32x4 a1 = {0.f, 0.f, 0.f, 0.f};
            f32x4 a2 = {0.f, 0.f, 0.f, 0.f};
#pragma unroll
            for (int tap = 0; tap < 9; ++tap) {
                const unsigned short* at = arow + ((tap / 3 - 1) * RSB + (tap % 3 - 1)) * 96;
#pragma unroll
                for (int kc = 0; kc < 3; ++kc) {
                    short8 a  = *(const short8*)(at + kc * 32);
                    short8 b0 = *(const short8*)(wb + ((0 * 9 + tap) * 3 + kc) * 512);
                    short8 b1 = *(const short8*)(wb + ((1 * 9 + tap) * 3 + kc) * 512);
                    short8 b2 = *(const short8*)(wb + ((2 * 9 + tap) * 3 + kc) * 512);
                    a0 = __builtin_amdgcn_mfma_f32_16x16x32_bf16(a, b0, a0, 0, 0, 0);
                    a1 = __builtin_amdgcn_mfma_f32_16x16x32_bf16(a, b1, a1, 0, 0, 0);
                    a2 = __builtin_amdgcn_mfma_f32_16x16x32_bf16(a, b2, a2, 0, 0, 0);
                }
            }
#pragma unroll
            for (int r = 0; r < 4; ++r) {
                int pl = pf * 16 + klane * 4 + r;
                s_off[pl][nh * 48 + 0 * 16 + col] = a0[r];
                s_off[pl][nh * 48 + 1 * 16 + col] = a1[r];
                s_off[pl][nh * 48 + 2 * 16 + col] = a2[r];
            }
        }
        __syncthreads();

        // ---------------- phase B: DCN ----------------
        for (int sidx = w; sidx < 6; sidx += 4) {
            const int pf = sidx & 1, g = sidx >> 1;
            const int p = P0 + pf * 16 + col;
            const int y = p >> 7, x = p & 127;
            const int pl = pf * 16 + col;
            const int coct = klane * 8;

            const unsigned short* fgc = feat + g * 32 + coct;
            const unsigned short* wb = wdB + (size_t)g * 9 * 2 * 512 + lane * 8;

            int adr[9][4];
            float wgt[9][4];
#pragma unroll
            for (int k = 0; k < 9; ++k) {
                float dy = s_off[pl][g * 9 + k];
                float dx = s_off[pl][27 + g * 9 + k];
                float mr = s_off[pl][54 + g * 9 + k];
                float m = 1.f / (1.f + __expf(-mr));

                float py = dy + (float)y + (float)(k / 3 - 1);
                float px = dx + (float)x + (float)(k % 3 - 1);
                float y0f = floorf(py), x0f = floorf(px);
                float fy = py - y0f, fx = px - x0f;
                float gy = 1.f - fy, gx = 1.f - fx;

                int py0 = (int)y0f + 1, px0 = (int)x0f + 1;
                int iy0 = min(max(py0, 0), 129);
                int iy1 = min(max(py0 + 1, 0), 129);
                int ix0 = min(max(px0, 0), 129);
                int ix1 = min(max(px0 + 1, 0), 129);

                wgt[k][0] = gy * gx * m;
                wgt[k][1] = gy * fx * m;
                wgt[k][2] = fy * gx * m;
                wgt[k][3] = fy * fx * m;

                adr[k][0] = iy0 * RSB + ix0;
                adr[k][1] = iy0 * RSB + ix1;
                adr[k][2] = iy1 * RSB + ix0;
                adr[k][3] = iy1 * RSB + ix1;
            }

            f32x4 acc0 = {0.f, 0.f, 0.f, 0.f};
            f32x4 acc1 = {0.f, 0.f, 0.f, 0.f};

            ushort8v ga[4], gb[4], gc[4];
#define LDG(buf, kk) { \
            buf[0] = *(const ushort8v*)(fgc + (size_t)adr[kk][0] * 96); \
            buf[1] = *(const ushort8v*)(fgc + (size_t)adr[kk][1] * 96); \
            buf[2] = *(const ushort8v*)(fgc + (size_t)adr[kk][2] * 96); \
            buf[3] = *(const ushort8v*)(fgc + (size_t)adr[kk][3] * 96); }
#define CMP(buf, kk) { \
            short8 a; \
            _Pragma("unroll") for (int j = 0; j < 8; ++j) { \
                float val = fmaf(wgt[kk][0], b2f(buf[0][j]), \
                            fmaf(wgt[kk][1], b2f(buf[1][j]), \
                            fmaf(wgt[kk][2], b2f(buf[2][j]), \
                                 wgt[kk][3] * b2f(buf[3][j])))); \
                a[j] = (short)f2b(val); } \
            short8 b0 = *(const short8*)(wb + ((kk) * 2 + 0) * 512); \
            short8 b1 = *(const short8*)(wb + ((kk) * 2 + 1) * 512); \
            acc0 = __builtin_amdgcn_mfma_f32_16x16x32_bf16(a, b0, acc0, 0, 0, 0); \
            acc1 = __builtin_amdgcn_mfma_f32_16x16x32_bf16(a, b1, acc1, 0, 0, 0); }

            LDG(ga, 0); LDG(gb, 1); LDG(gc, 2);
            CMP(ga, 0); LDG(ga, 3);
            CMP(gb, 1); LDG(gb, 4);
            CMP(gc, 2); LDG(gc, 5);
            CMP(ga, 3); LDG(ga, 6);
            CMP(gb, 4); LDG(gb, 7);
            CMP(gc, 5); LDG(gc, 8);
            CMP(ga, 6); CMP(gb, 7); CMP(gc, 8);
#undef LDG
#undef CMP

#pragma unroll
            for (int r = 0; r < 4; ++r) {
                int pr = P0 + pf * 16 + klane * 4 + r;
                int ch0 = g * 32 + col, ch1 = g * 32 + 16 + col;
                float o0 = acc0[r] + b_d[ch0];
                float o1 = acc1[r] + b_d[ch1];
                if (!last) {
                    int yy = pr >> 7, xx = pr & 127;
                    unsigned short* fo = (unsigned short*)outp;
                    size_t base = (size_t)((yy + 1) * RSB + (xx + 1)) * 96;
                    fo[base + ch0] = f2b(o0);
                    fo[base + ch1] = f2b(o1);
                } else {
                    float* fo = (float*)outp;
                    fo[(size_t)ch0 * HW + pr] = o0;
                    fo[(size_t)ch1 * HW + pr] = o1;
                }
            }
        }
        __syncthreads();   // protect s_off WAR across reps
    }
}

// ---------------------------------------------------------------------------
extern "C" void kernel_launch(void* const* d_in, const int* in_sizes, int n_in,
                              void* d_out, int out_size, void* d_ws, size_t ws_size,
                              hipStream_t stream) {
    const float* X1    = (const float*)d_in[0];
    const float* X2    = (const float*)d_in[1];
    const float* w_bot = (const float*)d_in[2];
    const float* wo0 = (const float*)d_in[3],  *wo1 = (const float*)d_in[6],
               *wo2 = (const float*)d_in[9],  *wo3 = (const float*)d_in[12];
    const float* wd0 = (const float*)d_in[4],  *wd1 = (const float*)d_in[7],
               *wd2 = (const float*)d_in[10], *wd3 = (const float*)d_in[13];
    const float* bd[4] = {(const float*)d_in[5], (const float*)d_in[8],
                          (const float*)d_in[11], (const float*)d_in[14]};

    unsigned short* in_nhwc = (unsigned short*)d_ws;          // 3,244,800
    unsigned short* featA   = in_nhwc + 3244800;              // 1,622,400
    unsigned short* featB   = featA + 1622400;                // 1,622,400
    unsigned short* wBbot   = featB + 1622400;                // 165,888
    unsigned short* wBoff   = wBbot + 165888;                 // 4 x 82,944
    unsigned short* wdB     = wBoff + 4 * 82944;              // 4 x 27,648

    prep_all<<<512, 256, 0, stream>>>(X1, X2, w_bot, wo0, wo1, wo2, wo3,
                                      wd0, wd1, wd2, wd3,
                                      wBbot, wBoff, wdB, in_nhwc, featA, featB, REP);
    conv_bot<<<512, 256, 0, stream>>>(in_nhwc, wBbot, featA, REP);

    unsigned short* cur = featA;
    unsigned short* nxt = featB;
    for (int it = 0; it < 4; ++it) {
        void* outp = (it == 3) ? d_out : (void*)nxt;
        offdcn_kernel<<<512, 256, 0, stream>>>(cur, wBoff + it * 82944,
                                               wdB + it * 27648, bd[it],
                                               outp, it == 3 ? 1 : 0, REP);
        unsigned short* t = cur; cur = nxt; nxt = t;
    }
}

// Round 16
// 151.644 us; speedup vs baseline: 10.1317x; 10.1317x over previous
//
#include <hip/hip_runtime.h>

#define HW 16384   // 128*128
#define RSB 130    // padded row stride (pixels)

typedef short short8 __attribute__((ext_vector_type(8)));
typedef float f32x4 __attribute__((ext_vector_type(4)));
typedef unsigned short ushort8v __attribute__((ext_vector_type(8)));

__device__ __forceinline__ float b2f(unsigned short u) {
    return __uint_as_float(((unsigned)u) << 16);
}
__device__ __forceinline__ unsigned short f2b(float f) {
    unsigned u = __float_as_uint(f);
    return (unsigned short)((u + 0x7fffu + ((u >> 16) & 1u)) >> 16);
}

// ---------------------------------------------------------------------------
// One-shot prep: weight B-fragments + NHWC pack + border zeroing.  (r12)
// ---------------------------------------------------------------------------
__global__ __launch_bounds__(256) void prep_all(
    const float* __restrict__ X1, const float* __restrict__ X2,
    const float* __restrict__ w_bot,
    const float* __restrict__ wo0, const float* __restrict__ wo1,
    const float* __restrict__ wo2, const float* __restrict__ wo3,
    const float* __restrict__ wd0, const float* __restrict__ wd1,
    const float* __restrict__ wd2, const float* __restrict__ wd3,
    unsigned short* __restrict__ wBbot, unsigned short* __restrict__ wBoff,
    unsigned short* __restrict__ wdB,  unsigned short* __restrict__ in_nhwc,
    unsigned short* __restrict__ featA, unsigned short* __restrict__ featB) {
    const int N0 = 165888, N1 = N0 + 331776, N2 = N1 + 110592,
              N3 = N2 + 393216, N4 = N3 + 24768;
    for (int idx = blockIdx.x * 256 + threadIdx.x; idx < N4; idx += 131072) {
        if (idx < N0) {
            int i = idx;
            int v = i & 7, lane = (i >> 3) & 63, t = i >> 9;
            int kc = t % 6; t /= 6;
            int tap = t % 9, nt = t / 9;
            int oc = nt * 16 + (lane & 15), cin = kc * 32 + (lane >> 4) * 8 + v;
            wBbot[i] = f2b(oc < 96 ? w_bot[(oc * 192 + cin) * 9 + tap] : 0.f);
        } else if (idx < N1) {
            int j = idx - N0;
            int l = j / 82944, i = j - l * 82944;
            const float* w = l == 0 ? wo0 : l == 1 ? wo1 : l == 2 ? wo2 : wo3;
            int v = i & 7, lane = (i >> 3) & 63, t = i >> 9;
            int kc = t % 3; t /= 3;
            int tap = t % 9, nt = t / 9;
            int oc = nt * 16 + (lane & 15), cin = kc * 32 + (lane >> 4) * 8 + v;
            wBoff[j] = f2b(oc < 81 ? w[(oc * 96 + cin) * 9 + tap] : 0.f);
        } else if (idx < N2) {
            int j = idx - N1;
            int l = j / 27648, i = j - l * 27648;
            const float* w = l == 0 ? wd0 : l == 1 ? wd1 : l == 2 ? wd2 : wd3;
            int v = i & 7, lane = (i >> 3) & 63, t = i >> 9;
            int nt = t & 1; t >>= 1;
            int tap = t % 9, g = t / 9;
            int oc = nt * 16 + (lane & 15), c = (lane >> 4) * 8 + v;
            wdB[j] = f2b(w[((g * 32 + oc) * 32 + c) * 9 + tap]);
        } else if (idx < N3) {
            int j = idx - N2;
            int cb = j >> 14, p = j & (HW - 1);
            int ch = cb * 8;
            int y = p >> 7, x = p & 127;
            ushort8v o;
#pragma unroll
            for (int q = 0; q < 8; ++q) {
                int c = ch + q;
                float v = (c < 96) ? X1[c * HW + p] : X2[(c - 96) * HW + p];
                o[q] = f2b(v);
            }
            *(ushort8v*)(in_nhwc + (size_t)((y + 1) * RSB + (x + 1)) * 192 + ch) = o;
        } else {
            int j = idx - N3;
            int bp = j / 48, c8 = j - bp * 48;
            int y, x;
            if (bp < 130)      { y = 0;   x = bp; }
            else if (bp < 260) { y = 129; x = bp - 130; }
            else { int t2 = bp - 260; y = 1 + (t2 >> 1); x = (t2 & 1) ? 129 : 0; }
            size_t pix = (size_t)y * RSB + x;
            ushort8v z = {0, 0, 0, 0, 0, 0, 0, 0};
            if (c8 < 24)      *(ushort8v*)(in_nhwc + pix * 192 + c8 * 8) = z;
            else if (c8 < 36) *(ushort8v*)(featA + pix * 96 + (c8 - 24) * 8) = z;
            else              *(ushort8v*)(featB + pix * 96 + (c8 - 36) * 8) = z;
        }
    }
}

// ---------------------------------------------------------------------------
// Bottom conv (192 -> 96).  FAT WAVES: wave = 64 px (4 m-frags) x 32 oc
// (2 nt) -> B-slab per wave 54 KB read for 4x the pixels (was 162 KB / 16 px).
// Block = 192 thr (3 waves = 3 oc-groups, SAME 64 px -> A L1-shared).
// Grid 256, XCD-swizzled 16-row bands.
// ---------------------------------------------------------------------------
__global__ __launch_bounds__(192) void conv_bot(const unsigned short* __restrict__ in,
                                                const unsigned short* __restrict__ wB,
                                                unsigned short* __restrict__ outb) {
    const int tid = threadIdx.x;
    const int lane = tid & 63;
    const int w = tid >> 6;                      // oc-group 0..2
    const int col = lane & 15, klane = lane >> 4;
    const int pb = ((blockIdx.x & 7) << 5) + (blockIdx.x >> 3);
    const int P0 = pb * 64;

    const unsigned short* arow[4];
#pragma unroll
    for (int mf = 0; mf < 4; ++mf) {
        int p = P0 + mf * 16 + col;
        int y = p >> 7, x = p & 127;
        arow[mf] = in + (size_t)((y + 1) * RSB + (x + 1)) * 192 + klane * 8;
    }
    const int nt0 = 2 * w;
    const unsigned short* wb = wB + (size_t)nt0 * 9 * 6 * 512 + lane * 8;

    f32x4 acc[4][2];
#pragma unroll
    for (int mf = 0; mf < 4; ++mf)
#pragma unroll
        for (int n = 0; n < 2; ++n) acc[mf][n] = (f32x4){0.f, 0.f, 0.f, 0.f};

#pragma unroll
    for (int tap = 0; tap < 9; ++tap) {
        const int toff = ((tap / 3 - 1) * RSB + (tap % 3 - 1)) * 192;
#pragma unroll
        for (int kc = 0; kc < 6; ++kc) {
            short8 b0 = *(const short8*)(wb + ((0 * 9 + tap) * 6 + kc) * 512);
            short8 b1 = *(const short8*)(wb + ((1 * 9 + tap) * 6 + kc) * 512);
#pragma unroll
            for (int mf = 0; mf < 4; ++mf) {
                short8 a = *(const short8*)(arow[mf] + toff + kc * 32);
                acc[mf][0] = __builtin_amdgcn_mfma_f32_16x16x32_bf16(a, b0, acc[mf][0], 0, 0, 0);
                acc[mf][1] = __builtin_amdgcn_mfma_f32_16x16x32_bf16(a, b1, acc[mf][1], 0, 0, 0);
            }
        }
    }

#pragma unroll
    for (int mf = 0; mf < 4; ++mf)
#pragma unroll
        for (int r = 0; r < 4; ++r) {
            int pr = P0 + mf * 16 + klane * 4 + r;
            int yy = pr >> 7, xx = pr & 127;
            size_t base = (size_t)((yy + 1) * RSB + (xx + 1)) * 96;
            outb[base + (nt0 + 0) * 16 + col] = f2b(acc[mf][0][r]);
            outb[base + (nt0 + 1) * 16 + col] = f2b(acc[mf][1][r]);
        }
}

// ---------------------------------------------------------------------------
// FUSED offset-conv + DCN layer, FAT WAVES.  Block = 192 thr (3 waves),
// 64 px/block, grid 256 XCD-swizzled.
// Phase A: wave w -> offset-conv oc [32w,32w+32), 4 m-frags -> f32 LDS.
// Phase B: wave w -> group g=w, 4 m-frags sequentially; dcn B-slab (18 KB,
// L1-resident) re-read per m-frag.  Zero-border clamp addressing (exact).
// ---------------------------------------------------------------------------
__global__ __launch_bounds__(192) void offdcn_kernel(
    const unsigned short* __restrict__ feat,
    const unsigned short* __restrict__ wBoff,
    const unsigned short* __restrict__ wdB,
    const float* __restrict__ b_d,
    void* __restrict__ outp, int last) {
    __shared__ float s_off[64][97];

    const int tid = threadIdx.x;
    const int lane = tid & 63;
    const int w = tid >> 6;                       // wave 0..2
    const int col = lane & 15, klane = lane >> 4;
    const int pb = ((blockIdx.x & 7) << 5) + (blockIdx.x >> 3);
    const int P0 = pb * 64;

    // ---------------- phase A: offset conv (4 m-frags x 2 nt) ----------------
    {
        const unsigned short* arow[4];
#pragma unroll
        for (int mf = 0; mf < 4; ++mf) {
            int p = P0 + mf * 16 + col;
            int y = p >> 7, x = p & 127;
            arow[mf] = feat + (size_t)((y + 1) * RSB + (x + 1)) * 96 + klane * 8;
        }
        const int nt0 = 2 * w;
        const unsigned short* wb = wBoff + (size_t)nt0 * 9 * 3 * 512 + lane * 8;

        f32x4 acc[4][2];
#pragma unroll
        for (int mf = 0; mf < 4; ++mf)
#pragma unroll
            for (int n = 0; n < 2; ++n) acc[mf][n] = (f32x4){0.f, 0.f, 0.f, 0.f};

#pragma unroll
        for (int tap = 0; tap < 9; ++tap) {
            const int toff = ((tap / 3 - 1) * RSB + (tap % 3 - 1)) * 96;
#pragma unroll
            for (int kc = 0; kc < 3; ++kc) {
                short8 b0 = *(const short8*)(wb + ((0 * 9 + tap) * 3 + kc) * 512);
                short8 b1 = *(const short8*)(wb + ((1 * 9 + tap) * 3 + kc) * 512);
#pragma unroll
                for (int mf = 0; mf < 4; ++mf) {
                    short8 a = *(const short8*)(arow[mf] + toff + kc * 32);
                    acc[mf][0] = __builtin_amdgcn_mfma_f32_16x16x32_bf16(a, b0, acc[mf][0], 0, 0, 0);
                    acc[mf][1] = __builtin_amdgcn_mfma_f32_16x16x32_bf16(a, b1, acc[mf][1], 0, 0, 0);
                }
            }
        }
#pragma unroll
        for (int mf = 0; mf < 4; ++mf)
#pragma unroll
            for (int r = 0; r < 4; ++r) {
                int pl = mf * 16 + klane * 4 + r;
                s_off[pl][(nt0 + 0) * 16 + col] = acc[mf][0][r];
                s_off[pl][(nt0 + 1) * 16 + col] = acc[mf][1][r];
            }
    }
    __syncthreads();

    // ---------------- phase B: DCN (wave w = group g), 4 m-frags ----------------
    {
        const int g = w;
        const int coct = klane * 8;
        const unsigned short* fgc = feat + g * 32 + coct;
        const unsigned short* wb = wdB + (size_t)g * 9 * 2 * 512 + lane * 8;

#pragma unroll 1
        for (int mf = 0; mf < 4; ++mf) {
            const int p = P0 + mf * 16 + col;
            const int y = p >> 7, x = p & 127;
            const int pl = mf * 16 + col;

            int adr[9][4];
            float wgt[9][4];
#pragma unroll
            for (int k = 0; k < 9; ++k) {
                float dy = s_off[pl][g * 9 + k];
                float dx = s_off[pl][27 + g * 9 + k];
                float mr = s_off[pl][54 + g * 9 + k];
                float m = 1.f / (1.f + __expf(-mr));

                float py = dy + (float)y + (float)(k / 3 - 1);
                float px = dx + (float)x + (float)(k % 3 - 1);
                float y0f = floorf(py), x0f = floorf(px);
                float fy = py - y0f, fx = px - x0f;
                float gy = 1.f - fy, gx = 1.f - fx;

                int py0 = (int)y0f + 1, px0 = (int)x0f + 1;   // padded coords
                int iy0 = min(max(py0, 0), 129);
                int iy1 = min(max(py0 + 1, 0), 129);
                int ix0 = min(max(px0, 0), 129);
                int ix1 = min(max(px0 + 1, 0), 129);

                wgt[k][0] = gy * gx * m;
                wgt[k][1] = gy * fx * m;
                wgt[k][2] = fy * gx * m;
                wgt[k][3] = fy * fx * m;

                adr[k][0] = iy0 * RSB + ix0;
                adr[k][1] = iy0 * RSB + ix1;
                adr[k][2] = iy1 * RSB + ix0;
                adr[k][3] = iy1 * RSB + ix1;
            }

            f32x4 acc0 = {0.f, 0.f, 0.f, 0.f};
            f32x4 acc1 = {0.f, 0.f, 0.f, 0.f};

            ushort8v ga[4], gb[4], gc[4];
#define LDG(buf, kk) { \
            buf[0] = *(const ushort8v*)(fgc + (size_t)adr[kk][0] * 96); \
            buf[1] = *(const ushort8v*)(fgc + (size_t)adr[kk][1] * 96); \
            buf[2] = *(const ushort8v*)(fgc + (size_t)adr[kk][2] * 96); \
            buf[3] = *(const ushort8v*)(fgc + (size_t)adr[kk][3] * 96); }
#define CMP(buf, kk) { \
            short8 a; \
            _Pragma("unroll") for (int j = 0; j < 8; ++j) { \
                float val = fmaf(wgt[kk][0], b2f(buf[0][j]), \
                            fmaf(wgt[kk][1], b2f(buf[1][j]), \
                            fmaf(wgt[kk][2], b2f(buf[2][j]), \
                                 wgt[kk][3] * b2f(buf[3][j])))); \
                a[j] = (short)f2b(val); } \
            short8 b0 = *(const short8*)(wb + ((kk) * 2 + 0) * 512); \
            short8 b1 = *(const short8*)(wb + ((kk) * 2 + 1) * 512); \
            acc0 = __builtin_amdgcn_mfma_f32_16x16x32_bf16(a, b0, acc0, 0, 0, 0); \
            acc1 = __builtin_amdgcn_mfma_f32_16x16x32_bf16(a, b1, acc1, 0, 0, 0); }

            LDG(ga, 0); LDG(gb, 1); LDG(gc, 2);
            CMP(ga, 0); LDG(ga, 3);
            CMP(gb, 1); LDG(gb, 4);
            CMP(gc, 2); LDG(gc, 5);
            CMP(ga, 3); LDG(ga, 6);
            CMP(gb, 4); LDG(gb, 7);
            CMP(gc, 5); LDG(gc, 8);
            CMP(ga, 6); CMP(gb, 7); CMP(gc, 8);
#undef LDG
#undef CMP

#pragma unroll
            for (int r = 0; r < 4; ++r) {
                int pr = P0 + mf * 16 + klane * 4 + r;
                int ch0 = g * 32 + col, ch1 = g * 32 + 16 + col;
                float o0 = acc0[r] + b_d[ch0];
                float o1 = acc1[r] + b_d[ch1];
                if (!last) {
                    int yy = pr >> 7, xx = pr & 127;
                    unsigned short* fo = (unsigned short*)outp;
                    size_t base = (size_t)((yy + 1) * RSB + (xx + 1)) * 96;
                    fo[base + ch0] = f2b(o0);
                    fo[base + ch1] = f2b(o1);
                } else {
                    float* fo = (float*)outp;
                    fo[(size_t)ch0 * HW + pr] = o0;
                    fo[(size_t)ch1 * HW + pr] = o1;
                }
            }
        }
    }
}

// ---------------------------------------------------------------------------
extern "C" void kernel_launch(void* const* d_in, const int* in_sizes, int n_in,
                              void* d_out, int out_size, void* d_ws, size_t ws_size,
                              hipStream_t stream) {
    const float* X1    = (const float*)d_in[0];
    const float* X2    = (const float*)d_in[1];
    const float* w_bot = (const float*)d_in[2];
    const float* wo0 = (const float*)d_in[3],  *wo1 = (const float*)d_in[6],
               *wo2 = (const float*)d_in[9],  *wo3 = (const float*)d_in[12];
    const float* wd0 = (const float*)d_in[4],  *wd1 = (const float*)d_in[7],
               *wd2 = (const float*)d_in[10], *wd3 = (const float*)d_in[13];
    const float* bd[4] = {(const float*)d_in[5], (const float*)d_in[8],
                          (const float*)d_in[11], (const float*)d_in[14]};

    unsigned short* in_nhwc = (unsigned short*)d_ws;          // 3,244,800
    unsigned short* featA   = in_nhwc + 3244800;              // 1,622,400
    unsigned short* featB   = featA + 1622400;                // 1,622,400
    unsigned short* wBbot   = featB + 1622400;                // 165,888
    unsigned short* wBoff   = wBbot + 165888;                 // 4 x 82,944
    unsigned short* wdB     = wBoff + 4 * 82944;              // 4 x 27,648
    // total 7,097,856 ushorts = 14.2 MB

    prep_all<<<512, 256, 0, stream>>>(X1, X2, w_bot, wo0, wo1, wo2, wo3,
                                      wd0, wd1, wd2, wd3,
                                      wBbot, wBoff, wdB, in_nhwc, featA, featB);
    conv_bot<<<256, 192, 0, stream>>>(in_nhwc, wBbot, featA);

    unsigned short* cur = featA;
    unsigned short* nxt = featB;
    for (int it = 0; it < 4; ++it) {
        void* outp = (it == 3) ? d_out : (void*)nxt;
        offdcn_kernel<<<256, 192, 0, stream>>>(cur, wBoff + it * 82944,
                                               wdB + it * 27648, bd[it],
                                               outp, it == 3 ? 1 : 0);
        unsigned short* t = cur; cur = nxt; nxt = t;
    }
}

// Round 17
// 119.961 us; speedup vs baseline: 12.8075x; 1.2641x over previous
//
#include <hip/hip_runtime.h>

#define HW 16384   // 128*128
#define RSB 130    // padded row stride (pixels)

typedef short short8 __attribute__((ext_vector_type(8)));
typedef float f32x4 __attribute__((ext_vector_type(4)));
typedef unsigned short ushort8v __attribute__((ext_vector_type(8)));

typedef __attribute__((address_space(1))) const unsigned int* gas_ptr;
typedef __attribute__((address_space(3))) unsigned int* las_ptr;
#define GLOAD_LDS16(g, l) \
    __builtin_amdgcn_global_load_lds((gas_ptr)(const void*)(g), (las_ptr)(void*)(l), 16, 0, 0)

__device__ __forceinline__ float b2f(unsigned short u) {
    return __uint_as_float(((unsigned)u) << 16);
}
__device__ __forceinline__ unsigned short f2b(float f) {
    unsigned u = __float_as_uint(f);
    return (unsigned short)((u + 0x7fffu + ((u >> 16) & 1u)) >> 16);
}

// ---------------------------------------------------------------------------
// One-shot prep: weight B-fragments + NHWC pack + border zeroing.  (r12)
// ---------------------------------------------------------------------------
__global__ __launch_bounds__(256) void prep_all(
    const float* __restrict__ X1, const float* __restrict__ X2,
    const float* __restrict__ w_bot,
    const float* __restrict__ wo0, const float* __restrict__ wo1,
    const float* __restrict__ wo2, const float* __restrict__ wo3,
    const float* __restrict__ wd0, const float* __restrict__ wd1,
    const float* __restrict__ wd2, const float* __restrict__ wd3,
    unsigned short* __restrict__ wBbot, unsigned short* __restrict__ wBoff,
    unsigned short* __restrict__ wdB,  unsigned short* __restrict__ in_nhwc,
    unsigned short* __restrict__ featA, unsigned short* __restrict__ featB) {
    const int N0 = 165888, N1 = N0 + 331776, N2 = N1 + 110592,
              N3 = N2 + 393216, N4 = N3 + 24768;
    for (int idx = blockIdx.x * 256 + threadIdx.x; idx < N4; idx += 131072) {
        if (idx < N0) {
            int i = idx;
            int v = i & 7, lane = (i >> 3) & 63, t = i >> 9;
            int kc = t % 6; t /= 6;
            int tap = t % 9, nt = t / 9;
            int oc = nt * 16 + (lane & 15), cin = kc * 32 + (lane >> 4) * 8 + v;
            wBbot[i] = f2b(oc < 96 ? w_bot[(oc * 192 + cin) * 9 + tap] : 0.f);
        } else if (idx < N1) {
            int j = idx - N0;
            int l = j / 82944, i = j - l * 82944;
            const float* w = l == 0 ? wo0 : l == 1 ? wo1 : l == 2 ? wo2 : wo3;
            int v = i & 7, lane = (i >> 3) & 63, t = i >> 9;
            int kc = t % 3; t /= 3;
            int tap = t % 9, nt = t / 9;
            int oc = nt * 16 + (lane & 15), cin = kc * 32 + (lane >> 4) * 8 + v;
            wBoff[j] = f2b(oc < 81 ? w[(oc * 96 + cin) * 9 + tap] : 0.f);
        } else if (idx < N2) {
            int j = idx - N1;
            int l = j / 27648, i = j - l * 27648;
            const float* w = l == 0 ? wd0 : l == 1 ? wd1 : l == 2 ? wd2 : wd3;
            int v = i & 7, lane = (i >> 3) & 63, t = i >> 9;
            int nt = t & 1; t >>= 1;
            int tap = t % 9, g = t / 9;
            int oc = nt * 16 + (lane & 15), c = (lane >> 4) * 8 + v;
            wdB[j] = f2b(w[((g * 32 + oc) * 32 + c) * 9 + tap]);
        } else if (idx < N3) {
            int j = idx - N2;
            int cb = j >> 14, p = j & (HW - 1);
            int ch = cb * 8;
            int y = p >> 7, x = p & 127;
            ushort8v o;
#pragma unroll
            for (int q = 0; q < 8; ++q) {
                int c = ch + q;
                float v = (c < 96) ? X1[c * HW + p] : X2[(c - 96) * HW + p];
                o[q] = f2b(v);
            }
            *(ushort8v*)(in_nhwc + (size_t)((y + 1) * RSB + (x + 1)) * 192 + ch) = o;
        } else {
            int j = idx - N3;
            int bp = j / 48, c8 = j - bp * 48;
            int y, x;
            if (bp < 130)      { y = 0;   x = bp; }
            else if (bp < 260) { y = 129; x = bp - 130; }
            else { int t2 = bp - 260; y = 1 + (t2 >> 1); x = (t2 & 1) ? 129 : 0; }
            size_t pix = (size_t)y * RSB + x;
            ushort8v z = {0, 0, 0, 0, 0, 0, 0, 0};
            if (c8 < 24)      *(ushort8v*)(in_nhwc + pix * 192 + c8 * 8) = z;
            else if (c8 < 36) *(ushort8v*)(featA + pix * 96 + (c8 - 24) * 8) = z;
            else              *(ushort8v*)(featB + pix * 96 + (c8 - 36) * 8) = z;
        }
    }
}

// ---------------------------------------------------------------------------
// Bottom conv (192 -> 96).  r12 shape (512 blocks x 4 waves, 32 px, wave =
// 16px x 48oc) + B DOUBLE-BUFFERED IN LDS: per tap the 36 KB B slab (all
// 6 nt x 6 kc 1KB chunks) is staged via global_load_lds (9 chunks/wave),
// compute reads conflict-free ds_read_b128.  72 KB LDS -> 2 blocks/CU.
// Accumulation order identical to r12 -> bit-identical output.
// ---------------------------------------------------------------------------
__global__ __launch_bounds__(256) void conv_bot(const unsigned short* __restrict__ in,
                                                const unsigned short* __restrict__ wB,
                                                unsigned short* __restrict__ outb) {
    __shared__ unsigned short s_b[2][18432];     // [buf][(nt*6+kc)*512 + lane*8]

    const int tid = threadIdx.x;
    const int lane = tid & 63;
    const int wid = tid >> 6;
    const int msub = wid & 1, nh = wid >> 1;
    // XCD swizzle: 512 blocks = 8 xcd x 64 chunks -> contiguous 16-row bands
    const int pb = ((blockIdx.x & 7) << 6) + (blockIdx.x >> 3);
    const int pbase = pb * 32 + msub * 16;
    const int p = pbase + (lane & 15);
    const int y = p >> 7, x = p & 127;
    const int klane = lane >> 4;
    const unsigned short* arow = in + (size_t)((y + 1) * RSB + (x + 1)) * 192 + klane * 8;
    const int nt0 = nh * 3;
    const int col = lane & 15;

    // stage tap 0 into buf 0 (chunks c = nt*6+kc; global = ((nt*9+tap)*6+kc))
#pragma unroll
    for (int i = 0; i < 9; ++i) {
        int c = wid * 9 + i;
        int nt = c / 6, kc = c - nt * 6;
        const unsigned short* g = wB + ((size_t)(nt * 9 + 0) * 6 + kc) * 512 + lane * 8;
        GLOAD_LDS16(g, &s_b[0][c * 512]);
    }
    __syncthreads();

    f32x4 a0 = {0.f, 0.f, 0.f, 0.f};
    f32x4 a1 = {0.f, 0.f, 0.f, 0.f};
    f32x4 a2 = {0.f, 0.f, 0.f, 0.f};

#pragma unroll 1
    for (int tap = 0; tap < 9; ++tap) {
        const int cur = tap & 1;
        if (tap < 8) {                            // prefetch next tap's B slab
            const int nxt = cur ^ 1;
#pragma unroll
            for (int i = 0; i < 9; ++i) {
                int c = wid * 9 + i;
                int nt = c / 6, kc = c - nt * 6;
                const unsigned short* g = wB + ((size_t)(nt * 9 + tap + 1) * 6 + kc) * 512 + lane * 8;
                GLOAD_LDS16(g, &s_b[nxt][c * 512]);
            }
        }
        const int toff = ((tap / 3 - 1) * RSB + (tap % 3 - 1)) * 192;
#pragma unroll
        for (int kc = 0; kc < 6; ++kc) {
            short8 a  = *(const short8*)(arow + toff + kc * 32);
            short8 b0 = *(const short8*)(&s_b[cur][((nt0 + 0) * 6 + kc) * 512 + lane * 8]);
            short8 b1 = *(const short8*)(&s_b[cur][((nt0 + 1) * 6 + kc) * 512 + lane * 8]);
            short8 b2 = *(const short8*)(&s_b[cur][((nt0 + 2) * 6 + kc) * 512 + lane * 8]);
            a0 = __builtin_amdgcn_mfma_f32_16x16x32_bf16(a, b0, a0, 0, 0, 0);
            a1 = __builtin_amdgcn_mfma_f32_16x16x32_bf16(a, b1, a1, 0, 0, 0);
            a2 = __builtin_amdgcn_mfma_f32_16x16x32_bf16(a, b2, a2, 0, 0, 0);
        }
        __syncthreads();   // drains prefetch (vmcnt) + protects buf reuse
    }

#pragma unroll
    for (int r = 0; r < 4; ++r) {
        int pr = pbase + klane * 4 + r;
        int yy = pr >> 7, xx = pr & 127;
        size_t base = (size_t)((yy + 1) * RSB + (xx + 1)) * 96;
        outb[base + (nt0 + 0) * 16 + col] = f2b(a0[r]);
        outb[base + (nt0 + 1) * 16 + col] = f2b(a1[r]);
        outb[base + (nt0 + 2) * 16 + col] = f2b(a2[r]);
    }
}

// ---------------------------------------------------------------------------
// FUSED offset-conv + DCN layer (r12-exact, proven 119 us total).
// Block = 256 thr (4 waves) = 32 px; grid 512 (2 blocks/CU).
// Phase A: offset conv -> f32 offsets in LDS.  Phase B: DCN, zero-border
// clamp addressing + 3-deep pipelined gathers.
// ---------------------------------------------------------------------------
__global__ __launch_bounds__(256) void offdcn_kernel(
    const unsigned short* __restrict__ feat,
    const unsigned short* __restrict__ wBoff,
    const unsigned short* __restrict__ wdB,
    const float* __restrict__ b_d,
    void* __restrict__ outp, int last) {
    __shared__ float s_off[32][97];

    const int tid = threadIdx.x;
    const int lane = tid & 63;
    const int w = tid >> 6;
    const int col = lane & 15, klane = lane >> 4;
    const int pb = ((blockIdx.x & 7) << 6) + (blockIdx.x >> 3);
    const int P0 = pb * 32;

    // ---------------- phase A: offset conv ----------------
    {
        const int pf = w >> 1, nh = w & 1;
        const int p = P0 + pf * 16 + col;
        const int y = p >> 7, x = p & 127;
        const unsigned short* arow = feat + (size_t)((y + 1) * RSB + (x + 1)) * 96 + klane * 8;
        const unsigned short* wb = wBoff + (size_t)(nh * 3) * 9 * 3 * 512 + lane * 8;

        f32x4 a0 = {0.f, 0.f, 0.f, 0.f};
        f32x4 a1 = {0.f, 0.f, 0.f, 0.f};
        f32x4 a2 = {0.f, 0.f, 0.f, 0.f};
#pragma unroll
        for (int tap = 0; tap < 9; ++tap) {
            const unsigned short* at = arow + ((tap / 3 - 1) * RSB + (tap % 3 - 1)) * 96;
#pragma unroll
            for (int kc = 0; kc < 3; ++kc) {
                short8 a  = *(const short8*)(at + kc * 32);
                short8 b0 = *(const short8*)(wb + ((0 * 9 + tap) * 3 + kc) * 512);
                short8 b1 = *(const short8*)(wb + ((1 * 9 + tap) * 3 + kc) * 512);
                short8 b2 = *(const short8*)(wb + ((2 * 9 + tap) * 3 + kc) * 512);
                a0 = __builtin_amdgcn_mfma_f32_16x16x32_bf16(a, b0, a0, 0, 0, 0);
                a1 = __builtin_amdgcn_mfma_f32_16x16x32_bf16(a, b1, a1, 0, 0, 0);
                a2 = __builtin_amdgcn_mfma_f32_16x16x32_bf16(a, b2, a2, 0, 0, 0);
            }
        }
#pragma unroll
        for (int r = 0; r < 4; ++r) {
            int pl = pf * 16 + klane * 4 + r;
            s_off[pl][nh * 48 + 0 * 16 + col] = a0[r];
            s_off[pl][nh * 48 + 1 * 16 + col] = a1[r];
            s_off[pl][nh * 48 + 2 * 16 + col] = a2[r];
        }
    }
    __syncthreads();

    // ---------------- phase B: DCN ----------------
    for (int sidx = w; sidx < 6; sidx += 4) {
        const int pf = sidx & 1, g = sidx >> 1;
        const int p = P0 + pf * 16 + col;
        const int y = p >> 7, x = p & 127;
        const int pl = pf * 16 + col;
        const int coct = klane * 8;

        const unsigned short* fgc = feat + g * 32 + coct;
        const unsigned short* wb = wdB + (size_t)g * 9 * 2 * 512 + lane * 8;

        int adr[9][4];
        float wgt[9][4];
#pragma unroll
        for (int k = 0; k < 9; ++k) {
            float dy = s_off[pl][g * 9 + k];
            float dx = s_off[pl][27 + g * 9 + k];
            float mr = s_off[pl][54 + g * 9 + k];
            float m = 1.f / (1.f + __expf(-mr));

            float py = dy + (float)y + (float)(k / 3 - 1);
            float px = dx + (float)x + (float)(k % 3 - 1);
            float y0f = floorf(py), x0f = floorf(px);
            float fy = py - y0f, fx = px - x0f;
            float gy = 1.f - fy, gx = 1.f - fx;

            int py0 = (int)y0f + 1, px0 = (int)x0f + 1;
            int iy0 = min(max(py0, 0), 129);
            int iy1 = min(max(py0 + 1, 0), 129);
            int ix0 = min(max(px0, 0), 129);
            int ix1 = min(max(px0 + 1, 0), 129);

            wgt[k][0] = gy * gx * m;
            wgt[k][1] = gy * fx * m;
            wgt[k][2] = fy * gx * m;
            wgt[k][3] = fy * fx * m;

            adr[k][0] = iy0 * RSB + ix0;
            adr[k][1] = iy0 * RSB + ix1;
            adr[k][2] = iy1 * RSB + ix0;
            adr[k][3] = iy1 * RSB + ix1;
        }

        f32x4 acc0 = {0.f, 0.f, 0.f, 0.f};
        f32x4 acc1 = {0.f, 0.f, 0.f, 0.f};

        ushort8v ga[4], gb[4], gc[4];
#define LDG(buf, kk) { \
        buf[0] = *(const ushort8v*)(fgc + (size_t)adr[kk][0] * 96); \
        buf[1] = *(const ushort8v*)(fgc + (size_t)adr[kk][1] * 96); \
        buf[2] = *(const ushort8v*)(fgc + (size_t)adr[kk][2] * 96); \
        buf[3] = *(const ushort8v*)(fgc + (size_t)adr[kk][3] * 96); }
#define CMP(buf, kk) { \
        short8 a; \
        _Pragma("unroll") for (int j = 0; j < 8; ++j) { \
            float val = fmaf(wgt[kk][0], b2f(buf[0][j]), \
                        fmaf(wgt[kk][1], b2f(buf[1][j]), \
                        fmaf(wgt[kk][2], b2f(buf[2][j]), \
                             wgt[kk][3] * b2f(buf[3][j])))); \
            a[j] = (short)f2b(val); } \
        short8 b0 = *(const short8*)(wb + ((kk) * 2 + 0) * 512); \
        short8 b1 = *(const short8*)(wb + ((kk) * 2 + 1) * 512); \
        acc0 = __builtin_amdgcn_mfma_f32_16x16x32_bf16(a, b0, acc0, 0, 0, 0); \
        acc1 = __builtin_amdgcn_mfma_f32_16x16x32_bf16(a, b1, acc1, 0, 0, 0); }

        LDG(ga, 0); LDG(gb, 1); LDG(gc, 2);
        CMP(ga, 0); LDG(ga, 3);
        CMP(gb, 1); LDG(gb, 4);
        CMP(gc, 2); LDG(gc, 5);
        CMP(ga, 3); LDG(ga, 6);
        CMP(gb, 4); LDG(gb, 7);
        CMP(gc, 5); LDG(gc, 8);
        CMP(ga, 6); CMP(gb, 7); CMP(gc, 8);
#undef LDG
#undef CMP

#pragma unroll
        for (int r = 0; r < 4; ++r) {
            int pr = P0 + pf * 16 + klane * 4 + r;
            int ch0 = g * 32 + col, ch1 = g * 32 + 16 + col;
            float o0 = acc0[r] + b_d[ch0];
            float o1 = acc1[r] + b_d[ch1];
            if (!last) {
                int yy = pr >> 7, xx = pr & 127;
                unsigned short* fo = (unsigned short*)outp;
                size_t base = (size_t)((yy + 1) * RSB + (xx + 1)) * 96;
                fo[base + ch0] = f2b(o0);
                fo[base + ch1] = f2b(o1);
            } else {
                float* fo = (float*)outp;
                fo[(size_t)ch0 * HW + pr] = o0;
                fo[(size_t)ch1 * HW + pr] = o1;
            }
        }
    }
}

// ---------------------------------------------------------------------------
extern "C" void kernel_launch(void* const* d_in, const int* in_sizes, int n_in,
                              void* d_out, int out_size, void* d_ws, size_t ws_size,
                              hipStream_t stream) {
    const float* X1    = (const float*)d_in[0];
    const float* X2    = (const float*)d_in[1];
    const float* w_bot = (const float*)d_in[2];
    const float* wo0 = (const float*)d_in[3],  *wo1 = (const float*)d_in[6],
               *wo2 = (const float*)d_in[9],  *wo3 = (const float*)d_in[12];
    const float* wd0 = (const float*)d_in[4],  *wd1 = (const float*)d_in[7],
               *wd2 = (const float*)d_in[10], *wd3 = (const float*)d_in[13];
    const float* bd[4] = {(const float*)d_in[5], (const float*)d_in[8],
                          (const float*)d_in[11], (const float*)d_in[14]};

    unsigned short* in_nhwc = (unsigned short*)d_ws;          // 3,244,800
    unsigned short* featA   = in_nhwc + 3244800;              // 1,622,400
    unsigned short* featB   = featA + 1622400;                // 1,622,400
    unsigned short* wBbot   = featB + 1622400;                // 165,888
    unsigned short* wBoff   = wBbot + 165888;                 // 4 x 82,944
    unsigned short* wdB     = wBoff + 4 * 82944;              // 4 x 27,648
    // total 7,097,856 ushorts = 14.2 MB

    prep_all<<<512, 256, 0, stream>>>(X1, X2, w_bot, wo0, wo1, wo2, wo3,
                                      wd0, wd1, wd2, wd3,
                                      wBbot, wBoff, wdB, in_nhwc, featA, featB);
    conv_bot<<<512, 256, 0, stream>>>(in_nhwc, wBbot, featA);

    unsigned short* cur = featA;
    unsigned short* nxt = featB;
    for (int it = 0; it < 4; ++it) {
        void* outp = (it == 3) ? d_out : (void*)nxt;
        offdcn_kernel<<<512, 256, 0, stream>>>(cur, wBoff + it * 82944,
                                               wdB + it * 27648, bd[it],
                                               outp, it == 3 ? 1 : 0);
        unsigned short* t = cur; cur = nxt; nxt = t;
    }
}